// Round 5
// baseline (462.062 us; speedup 1.0000x reference)
//
#include <hip/hip_runtime.h>
#include <hip/hip_bf16.h>

#define TT 50
#define BB 64
#define SS 100
#define HH 512
#define VT 32000
#define VE 5000
#define LDC 37000          // VT + VE
#define MROWS 3200         // T*B
#define NTILE 125          // VT/256 column tiles
#define TSTR 136           // padded LDS tile stride (ushorts)

typedef __bf16 bf16x8 __attribute__((ext_vector_type(8)));
typedef float f32x4 __attribute__((ext_vector_type(4)));

__device__ __forceinline__ ushort f2bf(float f) {
    unsigned u = __float_as_uint(f);
    u += 0x7fffu + ((u >> 16) & 1u);   // RNE
    return (ushort)(u >> 16);
}
__device__ __forceinline__ float bflo(unsigned u) { return __uint_as_float(u << 16); }
__device__ __forceinline__ float bfhi(unsigned u) { return __uint_as_float(u & 0xffff0000u); }

// ---------------- pass 0: fp32 -> bf16 conversion of W and hidden ----------------
__global__ void convert_kernel(const float* __restrict__ W, const float* __restrict__ hid,
                               ushort* __restrict__ wsB, ushort* __restrict__ wsA) {
    int g = blockIdx.x * 256 + threadIdx.x;
    const int WG = 4096000;                      // W float4-groups
    float4 v;
    ushort* dst;
    if (g < WG) {
        v = ((const float4*)W)[g];
        dst = wsB + 4 * (size_t)g;
    } else {
        int h = g - WG;
        v = ((const float4*)hid)[h];
        dst = wsA + 4 * (size_t)h;
    }
    ushort4 o;
    o.x = f2bf(v.x); o.y = f2bf(v.y); o.z = f2bf(v.z); o.w = f2bf(v.w);
    *(ushort4*)dst = o;
}

// ---------------- pass 1: bf16 MFMA GEMM, 128x256 block, wave tile 64x128 ----------------
// C = A[3200x512] * B^T[32000x512] + bias.  BK=32, dbuf 2-phase with counted vmcnt.
// 4 waves: wr=w>>1 selects M-half (64 rows), wc=w&1 selects N-half (128 cols).
// Per wave K-step: 12 ds_read_b128 -> 32 MFMA (43.7 FLOP/LDS-byte vs 32 before).
__global__ __launch_bounds__(256) void gemm_kernel(const ushort* __restrict__ A,
                                                   const ushort* __restrict__ B,
                                                   const float* __restrict__ bias,
                                                   ushort* __restrict__ outu,
                                                   float* __restrict__ pm,
                                                   float* __restrict__ ps) {
    __shared__ char smem[49152];   // A dbuf [0,16384), B dbuf [16384,49152)  U  tileT 34.8KB
    const int tid  = threadIdx.x;
    const int w    = tid >> 6;
    const int lane = tid & 63;
    const int wr   = w >> 1, wc = w & 1;
    const int brow = blockIdx.y * 128;
    const int bcol = blockIdx.x * 256;
    const int lr   = lane & 15;
    const int kg   = lane >> 4;

    ushort* tileT = (ushort*)smem;
    // staging chunk ids: A 2/thread (512 chunks), B 4/thread (1024 chunks)
    const int a0 = tid, a1 = tid + 256;
    const int ar0 = a0 >> 2, ak0 = a0 & 3;
    const int ar1 = a1 >> 2, ak1 = a1 & 3;

    f32x4 acc[4][8];
#pragma unroll
    for (int m = 0; m < 4; ++m)
#pragma unroll
        for (int n = 0; n < 8; ++n)
            acc[m][n] = (f32x4){0.f, 0.f, 0.f, 0.f};

#define STAGE(buf, kt)                                                                      \
    do {                                                                                    \
        char* bA = smem + (buf) * 8192;                                                     \
        char* bB = smem + 16384 + (buf) * 16384;                                            \
        __builtin_amdgcn_global_load_lds(                                                   \
            (const __attribute__((address_space(1))) void*)(A + (size_t)(brow + ar0) * HH + (kt) * 32 + ak0 * 8), \
            (__attribute__((address_space(3))) void*)(bA + a0 * 16), 16, 0, 0);             \
        __builtin_amdgcn_global_load_lds(                                                   \
            (const __attribute__((address_space(1))) void*)(A + (size_t)(brow + ar1) * HH + (kt) * 32 + ak1 * 8), \
            (__attribute__((address_space(3))) void*)(bA + a1 * 16), 16, 0, 0);             \
        _Pragma("unroll")                                                                   \
        for (int j = 0; j < 4; ++j) {                                                       \
            int c = tid + j * 256;                                                          \
            int row = c >> 2, kc = c & 3;                                                   \
            __builtin_amdgcn_global_load_lds(                                               \
                (const __attribute__((address_space(1))) void*)(B + (size_t)(bcol + row) * HH + (kt) * 32 + kc * 8), \
                (__attribute__((address_space(3))) void*)(bB + c * 16), 16, 0, 0);          \
        }                                                                                   \
    } while (0)

    STAGE(0, 0);                                 // prologue
    for (int kt = 0; kt < 16; ++kt) {
        const int cur = kt & 1;
        if (kt < 15) {
            STAGE(cur ^ 1, kt + 1);              // next tile's 6 loads fly across barrier
            asm volatile("s_waitcnt vmcnt(6)" ::: "memory");   // cur's 6 done
        } else {
            asm volatile("s_waitcnt vmcnt(0)" ::: "memory");
        }
        __builtin_amdgcn_sched_barrier(0);
        __builtin_amdgcn_s_barrier();            // all waves: cur buffer ready
        __builtin_amdgcn_sched_barrier(0);

        const char* pa = smem + cur * 8192;
        const char* pb = smem + 16384 + cur * 16384;
        bf16x8 af[4], bfr[8];
#pragma unroll
        for (int m = 0; m < 4; ++m)
            af[m] = *(const bf16x8*)(pa + (wr * 64 + m * 16 + lr) * 64 + kg * 16);
#pragma unroll
        for (int n = 0; n < 8; ++n)
            bfr[n] = *(const bf16x8*)(pb + (wc * 128 + n * 16 + lr) * 64 + kg * 16);
#pragma unroll
        for (int m = 0; m < 4; ++m)
#pragma unroll
            for (int n = 0; n < 8; ++n)
                acc[m][n] = __builtin_amdgcn_mfma_f32_16x16x32_bf16(af[m], bfr[n], acc[m][n], 0, 0, 0);

        __builtin_amdgcn_sched_barrier(0);
        __builtin_amdgcn_s_barrier();            // all waves done reading cur
    }
#undef STAGE
    __syncthreads();                             // fence before tileT reuse of smem

    // ---- epilogue in two 128-col half-passes through unioned tileT ----
    const int prow = tid >> 1, phalf = tid & 1;
    float Mx = -1e30f, Sx = 0.f;
#pragma unroll
    for (int h = 0; h < 2; ++h) {
        if (wc == h) {                           // the 2 waves owning this half write it
#pragma unroll
            for (int n = 0; n < 8; ++n) {
                int col = n * 16 + lr;           // 0..127 within half
                float bv = bias[bcol + h * 128 + col];
#pragma unroll
                for (int m = 0; m < 4; ++m) {
                    int row0 = wr * 64 + m * 16 + kg * 4;
#pragma unroll
                    for (int r = 0; r < 4; ++r)
                        tileT[(row0 + r) * TSTR + col] = f2bf(acc[m][n][r] + bv);
                }
            }
        }
        __syncthreads();

        // coalesced bf16 store of this half (256B segments)
#pragma unroll
        for (int it = 0; it < 8; ++it) {
            int idx = it * 256 + tid;
            int row = idx >> 4, ch = idx & 15;
            uint4 v = *(const uint4*)(&tileT[row * TSTR + ch * 8]);
            *(uint4*)(outu + (size_t)(brow + row) * 74000 + 42000 + bcol + h * 128 + ch * 8) = v;
        }

        // per-row partial (max,sumexp) over this half's 128 cols, merged online
        {
            const ushort* trow = &tileT[prow * TSTR + phalf * 64];
            uint4 vv[8];
#pragma unroll
            for (int i = 0; i < 8; ++i) vv[i] = *(const uint4*)(trow + i * 8);
            float mx = -1e30f;
#pragma unroll
            for (int i = 0; i < 8; ++i) {
                mx = fmaxf(mx, fmaxf(fmaxf(bflo(vv[i].x), bfhi(vv[i].x)), fmaxf(bflo(vv[i].y), bfhi(vv[i].y))));
                mx = fmaxf(mx, fmaxf(fmaxf(bflo(vv[i].z), bfhi(vv[i].z)), fmaxf(bflo(vv[i].w), bfhi(vv[i].w))));
            }
            float sx = 0.f;
#pragma unroll
            for (int i = 0; i < 8; ++i) {
                sx += __expf(bflo(vv[i].x) - mx) + __expf(bfhi(vv[i].x) - mx)
                    + __expf(bflo(vv[i].y) - mx) + __expf(bfhi(vv[i].y) - mx)
                    + __expf(bflo(vv[i].z) - mx) + __expf(bfhi(vv[i].z) - mx)
                    + __expf(bflo(vv[i].w) - mx) + __expf(bfhi(vv[i].w) - mx);
            }
            float nm = fmaxf(Mx, mx);
            Sx = Sx * __expf(Mx - nm) + sx * __expf(mx - nm);
            Mx = nm;
        }
        __syncthreads();                         // tileT fully read before next half
    }

    // combine the two 64-col partials (phalf 0/1) and store
    {
        float om = __shfl_xor(Mx, 1), os = __shfl_xor(Sx, 1);
        float M = fmaxf(Mx, om);
        float S = Sx * __expf(Mx - M) + os * __expf(om - M);
        if (phalf == 0) {
            pm[(size_t)blockIdx.x * MROWS + brow + prow] = M;
            ps[(size_t)blockIdx.x * MROWS + brow + prow] = S;
        }
    }
}

// ---------------- pass 2 (fused): lse reduce + gate + scatter + in-place normalize ----
__global__ __launch_bounds__(256) void norm_ext_kernel(float* __restrict__ out,
                                                       const float* __restrict__ pm,
                                                       const float* __restrict__ ps,
                                                       const float* __restrict__ dec,
                                                       const float* __restrict__ wc,
                                                       const float* __restrict__ bcp,
                                                       const float* __restrict__ attn,
                                                       const int* __restrict__ cte) {
    const int r = blockIdx.x;
    const int t = threadIdx.x;
    const int w = t >> 6, lane = t & 63;
    __shared__ float sm[4], ssv[4], red[4];
    __shared__ float lse_sh, csh;
    __shared__ float bins[VE];                   // 20000 B

    // lse partials (125 of them)
    float m = -1e30f, s = 0.f;
    if (t < NTILE) {
        m = pm[(size_t)t * MROWS + r];
        s = ps[(size_t)t * MROWS + r];
    }
    for (int off = 1; off < 64; off <<= 1) {
        float om = __shfl_xor(m, off), os = __shfl_xor(s, off);
        float nm = fmaxf(m, om);
        s = s * __expf(m - nm) + os * __expf(om - nm);
        m = nm;
    }
    if (lane == 0) { sm[w] = m; ssv[w] = s; }

    // gate partial: dot(dec[r], Wc), 2 elems/thread
    {
        float part = dec[(size_t)r * HH + t] * wc[t]
                   + dec[(size_t)r * HH + t + 256] * wc[t + 256];
        for (int off = 1; off < 64; off <<= 1) part += __shfl_xor(part, off);
        if (lane == 0) red[w] = part;
    }
    for (int v = t; v < VE; v += 256) bins[v] = 0.f;
    __syncthreads();

    if (t == 0) {
        float M = sm[0], S = ssv[0];
        for (int i = 1; i < 4; ++i) {
            float nm = fmaxf(M, sm[i]);
            S = S * __expf(M - nm) + ssv[i] * __expf(sm[i] - nm);
            M = nm;
        }
        lse_sh = M + __logf(S);
        float g = red[0] + red[1] + red[2] + red[3] + bcp[0];
        csh = 1.f / (1.f + __expf(-g));
    }
    __syncthreads();
    const float l = lse_sh;
    const float c = csh;

    // ext scatter into LDS bins
    if (t < SS) {
        float aw = attn[(size_t)r * SS + t] * (1.f - c);
        int idx = cte[t * BB + (r & 63)];
        if (idx != 0) atomicAdd(&bins[idx], aw);
    }

    // in-place normalize sweep: bf16 (row tail) -> fp32 log-softmax (row head).
    // Safe: fp32 write of uint4-index iw clobbers bf16 index ir only if ir < 2*iw - 5248;
    // barriers every 2 iterations bound skew to 512 indices (needs 256n > 4226, max n=15).
    const uint4* gsrc = (const uint4*)((const ushort*)out + (size_t)r * 74000 + 42000);
    float4* orow = (float4*)(out + (size_t)r * LDC);
    for (int n = 0; n < 16; ++n) {
        int i = t + 256 * n;
        if (i < VT / 8) {
            uint4 v = gsrc[i];
            float4 a, b;
            a.x = bflo(v.x) - l; a.y = bfhi(v.x) - l;
            a.z = bflo(v.y) - l; a.w = bfhi(v.y) - l;
            b.x = bflo(v.z) - l; b.y = bfhi(v.z) - l;
            b.z = bflo(v.w) - l; b.w = bfhi(v.w) - l;
            orow[2 * i]     = a;
            orow[2 * i + 1] = b;
        }
        if ((n & 1) == 1) __syncthreads();
    }
    __syncthreads();

    float4* eo = (float4*)(out + (size_t)r * LDC + VT);
    for (int v = t; v < VE / 4; v += 256) {
        float4 x;
        x.x = __logf(fminf(fmaxf(bins[4 * v + 0], 0.001f), 0.999f));
        x.y = __logf(fminf(fmaxf(bins[4 * v + 1], 0.001f), 0.999f));
        x.z = __logf(fminf(fmaxf(bins[4 * v + 2], 0.001f), 0.999f));
        x.w = __logf(fminf(fmaxf(bins[4 * v + 3], 0.001f), 0.999f));
        eo[v] = x;
    }
}

extern "C" void kernel_launch(void* const* d_in, const int* in_sizes, int n_in,
                              void* d_out, int out_size, void* d_ws, size_t ws_size,
                              hipStream_t stream) {
    const float* hidden = (const float*)d_in[0];
    const float* dec    = (const float*)d_in[1];
    // d_in[2] = concat_c, unused by the reference
    const float* attn   = (const float*)d_in[3];
    const int*   cte    = (const int*)d_in[4];
    const float* W      = (const float*)d_in[5];
    const float* bias   = (const float*)d_in[6];
    const float* Wc     = (const float*)d_in[7];
    const float* bc     = (const float*)d_in[8];
    float* out = (float*)d_out;

    ushort* wsB = (ushort*)d_ws;                       // W bf16  [32000][512]  32.77 MB
    ushort* wsA = wsB + (size_t)VT * HH;               // hidden bf16 [3200][512] 3.28 MB
    float*  pm  = (float*)(wsA + (size_t)MROWS * HH);  // partial max [125][3200]
    float*  ps  = pm + (size_t)NTILE * MROWS;          // partial sum [125][3200]

    convert_kernel<<<17600, 256, 0, stream>>>(W, hidden, wsB, wsA);
    gemm_kernel<<<dim3(NTILE, 25), 256, 0, stream>>>(wsA, wsB, bias, (ushort*)out, pm, ps);
    norm_ext_kernel<<<MROWS, 256, 0, stream>>>(out, pm, ps, dec, Wc, bc, attn, cte);
}

// Round 6
// 441.720 us; speedup vs baseline: 1.0461x; 1.0461x over previous
//
#include <hip/hip_runtime.h>
#include <hip/hip_bf16.h>

#define TT 50
#define BB 64
#define SS 100
#define HH 512
#define VT 32000
#define VE 5000
#define LDC 37000          // VT + VE
#define MROWS 3200         // T*B
#define NTILE 125          // VT/256 column tiles
#define NROWT 25           // M/128 row tiles
#define NWG   3125         // NTILE*NROWT
#define TSTR 136           // padded LDS tile stride (ushorts)

typedef __bf16 bf16x8 __attribute__((ext_vector_type(8)));
typedef float f32x4 __attribute__((ext_vector_type(4)));

__device__ __forceinline__ ushort f2bf(float f) {
    unsigned u = __float_as_uint(f);
    u += 0x7fffu + ((u >> 16) & 1u);   // RNE
    return (ushort)(u >> 16);
}
__device__ __forceinline__ float bflo(unsigned u) { return __uint_as_float(u << 16); }
__device__ __forceinline__ float bfhi(unsigned u) { return __uint_as_float(u & 0xffff0000u); }

// ---------------- pass 0: fp32 -> bf16 conversion of W and hidden ----------------
__global__ void convert_kernel(const float* __restrict__ W, const float* __restrict__ hid,
                               ushort* __restrict__ wsB, ushort* __restrict__ wsA) {
    int g = blockIdx.x * 256 + threadIdx.x;
    const int WG = 4096000;                      // W float4-groups
    float4 v;
    ushort* dst;
    if (g < WG) {
        v = ((const float4*)W)[g];
        dst = wsB + 4 * (size_t)g;
    } else {
        int h = g - WG;
        v = ((const float4*)hid)[h];
        dst = wsA + 4 * (size_t)h;
    }
    ushort4 o;
    o.x = f2bf(v.x); o.y = f2bf(v.y); o.z = f2bf(v.z); o.w = f2bf(v.w);
    *(ushort4*)dst = o;
}

// ---------------- pass 1: bf16 MFMA GEMM, 128x256 block, wave tile 64x128 ----------------
// C = A[3200x512] * B^T[32000x512] + bias.  BK=32, dbuf 2-phase with counted vmcnt.
// LDS chunk swizzle: slot kc' holds global chunk kc = kc' ^ ((row>>1)&3)  (inverse-swz
// SOURCE, linear gload_lds dest, XOR'd read) -> ds_read_b128 2-way (free) vs 8-way.
// XCD-aware bijective remap (m204): 25 consecutive same-XCD blocks share one B panel.
__global__ __launch_bounds__(256) void gemm_kernel(const ushort* __restrict__ A,
                                                   const ushort* __restrict__ B,
                                                   const float* __restrict__ bias,
                                                   ushort* __restrict__ outu,
                                                   float* __restrict__ pm,
                                                   float* __restrict__ ps) {
    __shared__ char smem[49152];   // A dbuf [0,16384), B dbuf [16384,49152)  U  tileT 34.8KB
    const int tid  = threadIdx.x;
    const int w    = tid >> 6;
    const int lane = tid & 63;
    const int wr   = w >> 1, wc = w & 1;
    const int lr   = lane & 15;
    const int kg   = lane >> 4;
    const int kgs  = kg ^ ((lr >> 1) & 3);       // swizzled read slot (uniform in row base)

    // XCD-aware bijective remap: nwg=3125, q=390, r=5
    const int orig = blockIdx.x;
    const int xcd  = orig & 7, seq = orig >> 3;
    const int wgid = (xcd < 5 ? xcd * 391 : 5 * 391 + (xcd - 5) * 390) + seq;
    const int ct   = wgid / NROWT;               // column tile: 25 consecutive wgid share it
    const int rt   = wgid % NROWT;
    const int brow = rt * 128;
    const int bcol = ct * 256;

    ushort* tileT = (ushort*)smem;
    // staging: A 2 chunks/thread, B 4 chunks/thread; source chunk inverse-swizzled
    const int a0 = tid, a1 = tid + 256;
    const int ar0 = a0 >> 2, aks0 = (a0 & 3) ^ ((a0 >> 3) & 3);
    const int ar1 = a1 >> 2, aks1 = (a1 & 3) ^ ((a1 >> 3) & 3);

    f32x4 acc[4][8];
#pragma unroll
    for (int m = 0; m < 4; ++m)
#pragma unroll
        for (int n = 0; n < 8; ++n)
            acc[m][n] = (f32x4){0.f, 0.f, 0.f, 0.f};

#define STAGE(buf, kt)                                                                      \
    do {                                                                                    \
        char* bA = smem + (buf) * 8192;                                                     \
        char* bB = smem + 16384 + (buf) * 16384;                                            \
        __builtin_amdgcn_global_load_lds(                                                   \
            (const __attribute__((address_space(1))) void*)(A + (size_t)(brow + ar0) * HH + (kt) * 32 + aks0 * 8), \
            (__attribute__((address_space(3))) void*)(bA + a0 * 16), 16, 0, 0);             \
        __builtin_amdgcn_global_load_lds(                                                   \
            (const __attribute__((address_space(1))) void*)(A + (size_t)(brow + ar1) * HH + (kt) * 32 + aks1 * 8), \
            (__attribute__((address_space(3))) void*)(bA + a1 * 16), 16, 0, 0);             \
        _Pragma("unroll")                                                                   \
        for (int j = 0; j < 4; ++j) {                                                       \
            int c = tid + j * 256;                                                          \
            int row = c >> 2, kcs = (c & 3) ^ ((c >> 3) & 3);                               \
            __builtin_amdgcn_global_load_lds(                                               \
                (const __attribute__((address_space(1))) void*)(B + (size_t)(bcol + row) * HH + (kt) * 32 + kcs * 8), \
                (__attribute__((address_space(3))) void*)(bB + c * 16), 16, 0, 0);          \
        }                                                                                   \
    } while (0)

    STAGE(0, 0);                                 // prologue
    for (int kt = 0; kt < 16; ++kt) {
        const int cur = kt & 1;
        if (kt < 15) {
            STAGE(cur ^ 1, kt + 1);              // next tile's 6 loads fly across barrier
            asm volatile("s_waitcnt vmcnt(6)" ::: "memory");   // cur's 6 done
        } else {
            asm volatile("s_waitcnt vmcnt(0)" ::: "memory");
        }
        __builtin_amdgcn_sched_barrier(0);
        __builtin_amdgcn_s_barrier();            // all waves: cur buffer ready
        __builtin_amdgcn_sched_barrier(0);

        const char* pa = smem + cur * 8192;
        const char* pb = smem + 16384 + cur * 16384;
        bf16x8 af[4], bfr[8];
#pragma unroll
        for (int m = 0; m < 4; ++m)
            af[m] = *(const bf16x8*)(pa + (wr * 64 + m * 16 + lr) * 64 + kgs * 16);
#pragma unroll
        for (int n = 0; n < 8; ++n)
            bfr[n] = *(const bf16x8*)(pb + (wc * 128 + n * 16 + lr) * 64 + kgs * 16);
#pragma unroll
        for (int m = 0; m < 4; ++m)
#pragma unroll
            for (int n = 0; n < 8; ++n)
                acc[m][n] = __builtin_amdgcn_mfma_f32_16x16x32_bf16(af[m], bfr[n], acc[m][n], 0, 0, 0);

        __builtin_amdgcn_sched_barrier(0);
        __builtin_amdgcn_s_barrier();            // all waves done reading cur
    }
#undef STAGE
    __syncthreads();                             // fence before tileT reuse of smem

    // ---- epilogue in two 128-col half-passes through unioned tileT ----
    const int prow = tid >> 1, phalf = tid & 1;
    float Mx = -1e30f, Sx = 0.f;
#pragma unroll
    for (int h = 0; h < 2; ++h) {
        if (wc == h) {                           // the 2 waves owning this half write it
#pragma unroll
            for (int n = 0; n < 8; ++n) {
                int col = n * 16 + lr;           // 0..127 within half
                float bv = bias[bcol + h * 128 + col];
#pragma unroll
                for (int m = 0; m < 4; ++m) {
                    int row0 = wr * 64 + m * 16 + kg * 4;
#pragma unroll
                    for (int r = 0; r < 4; ++r)
                        tileT[(row0 + r) * TSTR + col] = f2bf(acc[m][n][r] + bv);
                }
            }
        }
        __syncthreads();

        // coalesced bf16 store of this half (256B segments)
#pragma unroll
        for (int it = 0; it < 8; ++it) {
            int idx = it * 256 + tid;
            int row = idx >> 4, ch = idx & 15;
            uint4 v = *(const uint4*)(&tileT[row * TSTR + ch * 8]);
            *(uint4*)(outu + (size_t)(brow + row) * 74000 + 42000 + bcol + h * 128 + ch * 8) = v;
        }

        // per-row partial (max,sumexp) over this half's 128 cols, merged online
        {
            const ushort* trow = &tileT[prow * TSTR + phalf * 64];
            uint4 vv[8];
#pragma unroll
            for (int i = 0; i < 8; ++i) vv[i] = *(const uint4*)(trow + i * 8);
            float mx = -1e30f;
#pragma unroll
            for (int i = 0; i < 8; ++i) {
                mx = fmaxf(mx, fmaxf(fmaxf(bflo(vv[i].x), bfhi(vv[i].x)), fmaxf(bflo(vv[i].y), bfhi(vv[i].y))));
                mx = fmaxf(mx, fmaxf(fmaxf(bflo(vv[i].z), bfhi(vv[i].z)), fmaxf(bflo(vv[i].w), bfhi(vv[i].w))));
            }
            float sx = 0.f;
#pragma unroll
            for (int i = 0; i < 8; ++i) {
                sx += __expf(bflo(vv[i].x) - mx) + __expf(bfhi(vv[i].x) - mx)
                    + __expf(bflo(vv[i].y) - mx) + __expf(bfhi(vv[i].y) - mx)
                    + __expf(bflo(vv[i].z) - mx) + __expf(bfhi(vv[i].z) - mx)
                    + __expf(bflo(vv[i].w) - mx) + __expf(bfhi(vv[i].w) - mx);
            }
            float nm = fmaxf(Mx, mx);
            Sx = Sx * __expf(Mx - nm) + sx * __expf(mx - nm);
            Mx = nm;
        }
        __syncthreads();                         // tileT fully read before next half
    }

    // combine the two 64-col partials (phalf 0/1) and store
    {
        float om = __shfl_xor(Mx, 1), os = __shfl_xor(Sx, 1);
        float M = fmaxf(Mx, om);
        float S = Sx * __expf(Mx - M) + os * __expf(om - M);
        if (phalf == 0) {
            pm[(size_t)ct * MROWS + brow + prow] = M;
            ps[(size_t)ct * MROWS + brow + prow] = S;
        }
    }
}

// ---------------- pass 2 (fused): lse reduce + gate + scatter + in-place normalize ----
__global__ __launch_bounds__(256) void norm_ext_kernel(float* __restrict__ out,
                                                       const float* __restrict__ pm,
                                                       const float* __restrict__ ps,
                                                       const float* __restrict__ dec,
                                                       const float* __restrict__ wc,
                                                       const float* __restrict__ bcp,
                                                       const float* __restrict__ attn,
                                                       const int* __restrict__ cte) {
    const int r = blockIdx.x;
    const int t = threadIdx.x;
    const int w = t >> 6, lane = t & 63;
    __shared__ float sm[4], ssv[4], red[4];
    __shared__ float lse_sh, csh;
    __shared__ float bins[VE];                   // 20000 B

    // lse partials (125 of them)
    float m = -1e30f, s = 0.f;
    if (t < NTILE) {
        m = pm[(size_t)t * MROWS + r];
        s = ps[(size_t)t * MROWS + r];
    }
    for (int off = 1; off < 64; off <<= 1) {
        float om = __shfl_xor(m, off), os = __shfl_xor(s, off);
        float nm = fmaxf(m, om);
        s = s * __expf(m - nm) + os * __expf(om - nm);
        m = nm;
    }
    if (lane == 0) { sm[w] = m; ssv[w] = s; }

    // gate partial: dot(dec[r], Wc), 2 elems/thread
    {
        float part = dec[(size_t)r * HH + t] * wc[t]
                   + dec[(size_t)r * HH + t + 256] * wc[t + 256];
        for (int off = 1; off < 64; off <<= 1) part += __shfl_xor(part, off);
        if (lane == 0) red[w] = part;
    }
    for (int v = t; v < VE; v += 256) bins[v] = 0.f;
    __syncthreads();

    if (t == 0) {
        float M = sm[0], S = ssv[0];
        for (int i = 1; i < 4; ++i) {
            float nm = fmaxf(M, sm[i]);
            S = S * __expf(M - nm) + ssv[i] * __expf(sm[i] - nm);
            M = nm;
        }
        lse_sh = M + __logf(S);
        float g = red[0] + red[1] + red[2] + red[3] + bcp[0];
        csh = 1.f / (1.f + __expf(-g));
    }
    __syncthreads();
    const float l = lse_sh;
    const float c = csh;

    // ext scatter into LDS bins
    if (t < SS) {
        float aw = attn[(size_t)r * SS + t] * (1.f - c);
        int idx = cte[t * BB + (r & 63)];
        if (idx != 0) atomicAdd(&bins[idx], aw);
    }

    // in-place normalize sweep: bf16 (row tail) -> fp32 log-softmax (row head).
    // Safe: fp32 write of uint4-index iw clobbers bf16 index ir only if ir < 2*iw - 5248;
    // barriers every 2 iterations bound skew to 512 indices (needs 256n > 4226, max n=15).
    const uint4* gsrc = (const uint4*)((const ushort*)out + (size_t)r * 74000 + 42000);
    float4* orow = (float4*)(out + (size_t)r * LDC);
    for (int n = 0; n < 16; ++n) {
        int i = t + 256 * n;
        if (i < VT / 8) {
            uint4 v = gsrc[i];
            float4 a, b;
            a.x = bflo(v.x) - l; a.y = bfhi(v.x) - l;
            a.z = bflo(v.y) - l; a.w = bfhi(v.y) - l;
            b.x = bflo(v.z) - l; b.y = bfhi(v.z) - l;
            b.z = bflo(v.w) - l; b.w = bfhi(v.w) - l;
            orow[2 * i]     = a;
            orow[2 * i + 1] = b;
        }
        if ((n & 1) == 1) __syncthreads();
    }
    __syncthreads();

    float4* eo = (float4*)(out + (size_t)r * LDC + VT);
    for (int v = t; v < VE / 4; v += 256) {
        float4 x;
        x.x = __logf(fminf(fmaxf(bins[4 * v + 0], 0.001f), 0.999f));
        x.y = __logf(fminf(fmaxf(bins[4 * v + 1], 0.001f), 0.999f));
        x.z = __logf(fminf(fmaxf(bins[4 * v + 2], 0.001f), 0.999f));
        x.w = __logf(fminf(fmaxf(bins[4 * v + 3], 0.001f), 0.999f));
        eo[v] = x;
    }
}

extern "C" void kernel_launch(void* const* d_in, const int* in_sizes, int n_in,
                              void* d_out, int out_size, void* d_ws, size_t ws_size,
                              hipStream_t stream) {
    const float* hidden = (const float*)d_in[0];
    const float* dec    = (const float*)d_in[1];
    // d_in[2] = concat_c, unused by the reference
    const float* attn   = (const float*)d_in[3];
    const int*   cte    = (const int*)d_in[4];
    const float* W      = (const float*)d_in[5];
    const float* bias   = (const float*)d_in[6];
    const float* Wc     = (const float*)d_in[7];
    const float* bc     = (const float*)d_in[8];
    float* out = (float*)d_out;

    ushort* wsB = (ushort*)d_ws;                       // W bf16  [32000][512]  32.77 MB
    ushort* wsA = wsB + (size_t)VT * HH;               // hidden bf16 [3200][512] 3.28 MB
    float*  pm  = (float*)(wsA + (size_t)MROWS * HH);  // partial max [125][3200]
    float*  ps  = pm + (size_t)NTILE * MROWS;          // partial sum [125][3200]

    convert_kernel<<<17600, 256, 0, stream>>>(W, hidden, wsB, wsA);
    gemm_kernel<<<NWG, 256, 0, stream>>>(wsA, wsB, bias, (ushort*)out, pm, ps);
    norm_ext_kernel<<<MROWS, 256, 0, stream>>>(out, pm, ps, dec, Wc, bc, attn, cte);
}

// Round 7
// 354.360 us; speedup vs baseline: 1.3039x; 1.2465x over previous
//
#include <hip/hip_runtime.h>
#include <hip/hip_bf16.h>

#define TT 50
#define BB 64
#define SS 100
#define HH 512
#define VT 32000
#define VE 5000
#define LDC 37000          // VT + VE
#define MROWS 3200         // T*B
#define MPAD 3328          // 13*256 (wsA padded rows)
#define NTILE 125          // VT/256 column tiles
#define NRT 13             // M row tiles of 256
#define NWG 1625           // NTILE*NRT
#define TSTR 264           // epilogue LDS tile stride (ushorts, 256+8 pad)

typedef __bf16 bf16x8 __attribute__((ext_vector_type(8)));
typedef float f32x4 __attribute__((ext_vector_type(4)));

__device__ __forceinline__ ushort f2bf(float f) {
    unsigned u = __float_as_uint(f);
    u += 0x7fffu + ((u >> 16) & 1u);   // RNE
    return (ushort)(u >> 16);
}
__device__ __forceinline__ float bflo(unsigned u) { return __uint_as_float(u << 16); }
__device__ __forceinline__ float bfhi(unsigned u) { return __uint_as_float(u & 0xffff0000u); }

// ---------------- pass 0: fp32 -> bf16 conversion of W and hidden (+ zero-pad) --------
__global__ void convert_kernel(const float* __restrict__ W, const float* __restrict__ hid,
                               ushort* __restrict__ wsB, ushort* __restrict__ wsA) {
    int g = blockIdx.x * 256 + threadIdx.x;
    const int WG = 4096000;                      // W float4-groups
    const int HG = 409600;                       // hidden float4-groups
    if (g < WG + HG) {
        float4 v;
        ushort* dst;
        if (g < WG) {
            v = ((const float4*)W)[g];
            dst = wsB + 4 * (size_t)g;
        } else {
            int h = g - WG;
            v = ((const float4*)hid)[h];
            dst = wsA + 4 * (size_t)h;
        }
        ushort4 o;
        o.x = f2bf(v.x); o.y = f2bf(v.y); o.z = f2bf(v.z); o.w = f2bf(v.w);
        *(ushort4*)dst = o;
    } else {
        int p = g - (WG + HG);                   // 0..16383: zero rows 3200..3327
        ushort4 z = {0, 0, 0, 0};
        *(ushort4*)(wsA + (size_t)HG * 4 + 4 * (size_t)p) = z;
    }
}

// ---------------- pass 1: bf16 MFMA GEMM, 256x256 block, 8 waves, phase-split ----------
// C = A[3328x512] * B^T[32000x512] + bias.  16 K-tiles of BK=32, 3-slot LDS ring
// (tile t in slot t%3), counted vmcnt(6) once per K-tile (drain 4->0 at tail only).
// Wave grid 2M x 4N, wave tile 128x64: 2 phases x 16 MFMA per K-tile.
// LDS read swizzle: slot' = kg ^ ((lr>>1)&3) with inverse-swizzled global source.
__global__ __launch_bounds__(512, 2) void gemm_kernel(const ushort* __restrict__ A,
                                                      const ushort* __restrict__ B,
                                                      const float* __restrict__ bias,
                                                      ushort* __restrict__ outu,
                                                      float* __restrict__ pm,
                                                      float* __restrict__ ps) {
    __shared__ char smem[98304];                 // ring A 3x16KB [0,49152) + B 3x16KB; U tileT
    const int tid  = threadIdx.x;
    const int wid  = tid >> 6;
    const int lane = tid & 63;
    const int wrow = wid >> 2, wcol = wid & 3;
    const int lr   = lane & 15;
    const int kg   = lane >> 4;
    const int kgs  = kg ^ ((lr >> 1) & 3);       // bank-balanced read slot

    // XCD-aware bijective remap: nwg=1625, q=203, r=1
    const int orig = blockIdx.x;
    const int xcd  = orig & 7, seq = orig >> 3;
    const int wgid = (xcd == 0 ? 0 : 204 + (xcd - 1) * 203) + seq;
    const int ct   = wgid / NRT;                 // 13 consecutive wgid share one B panel
    const int rt   = wgid - ct * NRT;
    const int brow = rt * 256;
    const int bcol = ct * 256;

    // staging ids: per matrix per K-tile, 1024 chunks of 16B; 2 chunks/thread
    const int c0 = tid, c1 = tid + 512;
    const int r0 = c0 >> 2, s0 = (c0 & 3) ^ ((r0 >> 1) & 3);   // inverse-swz source slot
    const int r1 = c1 >> 2, s1 = (c1 & 3) ^ ((r1 >> 1) & 3);

    f32x4 acc[8][4];
#pragma unroll
    for (int m = 0; m < 8; ++m)
#pragma unroll
        for (int n = 0; n < 4; ++n)
            acc[m][n] = (f32x4){0.f, 0.f, 0.f, 0.f};

#define LDSA(s) (smem + (s) * 16384)
#define LDSB(s) (smem + 49152 + (s) * 16384)
#define STAGE_A(slot, kt)                                                                   \
    do {                                                                                    \
        __builtin_amdgcn_global_load_lds(                                                   \
            (const __attribute__((address_space(1))) void*)(A + (size_t)(brow + r0) * HH + (kt) * 32 + s0 * 8), \
            (__attribute__((address_space(3))) void*)(LDSA(slot) + c0 * 16), 16, 0, 0);     \
        __builtin_amdgcn_global_load_lds(                                                   \
            (const __attribute__((address_space(1))) void*)(A + (size_t)(brow + r1) * HH + (kt) * 32 + s1 * 8), \
            (__attribute__((address_space(3))) void*)(LDSA(slot) + c1 * 16), 16, 0, 0);     \
    } while (0)
#define STAGE_B(slot, kt)                                                                   \
    do {                                                                                    \
        __builtin_amdgcn_global_load_lds(                                                   \
            (const __attribute__((address_space(1))) void*)(B + (size_t)(bcol + r0) * HH + (kt) * 32 + s0 * 8), \
            (__attribute__((address_space(3))) void*)(LDSB(slot) + c0 * 16), 16, 0, 0);     \
        __builtin_amdgcn_global_load_lds(                                                   \
            (const __attribute__((address_space(1))) void*)(B + (size_t)(bcol + r1) * HH + (kt) * 32 + s1 * 8), \
            (__attribute__((address_space(3))) void*)(LDSB(slot) + c1 * 16), 16, 0, 0);     \
    } while (0)

    // prologue: tiles 0 and 1 fully in flight (8 loads/thread)
    STAGE_A(0, 0); STAGE_B(0, 0); STAGE_A(1, 1); STAGE_B(1, 1);

    int slot = 0;
    for (int t = 0; t < 16; ++t) {
        const int sl2 = (slot + 2 >= 3) ? slot - 1 : slot + 2;   // (t+2)%3
        const char* pa = (const char*)LDSA(slot);
        const char* pb = (const char*)LDSB(slot);
        bf16x8 af[4], bf[4];

        // ---- phase A: stage A(t+2), counted wait, quadrant m0-3 x full N x K32 ----
        if (t < 14) {
            STAGE_A(sl2, t + 2);
            asm volatile("s_waitcnt vmcnt(6)" ::: "memory");   // retires S(t) fully
        } else if (t == 14) {
            asm volatile("s_waitcnt vmcnt(4)" ::: "memory");
        } else {
            asm volatile("s_waitcnt vmcnt(0)" ::: "memory");
        }
        __builtin_amdgcn_s_barrier();            // all waves: tile t resident
        asm volatile("" ::: "memory");
#pragma unroll
        for (int n = 0; n < 4; ++n)
            bf[n] = *(const bf16x8*)(pb + ((wcol * 64 + n * 16 + lr) * 64 + kgs * 16));
#pragma unroll
        for (int m = 0; m < 4; ++m)
            af[m] = *(const bf16x8*)(pa + ((wrow * 128 + m * 16 + lr) * 64 + kgs * 16));
        __builtin_amdgcn_sched_barrier(0);
        __builtin_amdgcn_s_setprio(1);
#pragma unroll
        for (int m = 0; m < 4; ++m)
#pragma unroll
            for (int n = 0; n < 4; ++n)
                acc[m][n] = __builtin_amdgcn_mfma_f32_16x16x32_bf16(af[m], bf[n], acc[m][n], 0, 0, 0);
        __builtin_amdgcn_s_setprio(0);
        asm volatile("" ::: "memory");
        __builtin_amdgcn_s_barrier();            // phase lock
        asm volatile("" ::: "memory");

        // ---- phase B: stage B(t+2), quadrant m4-7 (reuse bf regs) ----
        if (t < 14) STAGE_B(sl2, t + 2);
#pragma unroll
        for (int m = 0; m < 4; ++m)
            af[m] = *(const bf16x8*)(pa + ((wrow * 128 + 64 + m * 16 + lr) * 64 + kgs * 16));
        __builtin_amdgcn_sched_barrier(0);
        __builtin_amdgcn_s_setprio(1);
#pragma unroll
        for (int m = 0; m < 4; ++m)
#pragma unroll
            for (int n = 0; n < 4; ++n)
                acc[4 + m][n] = __builtin_amdgcn_mfma_f32_16x16x32_bf16(af[m], bf[n], acc[4 + m][n], 0, 0, 0);
        __builtin_amdgcn_s_setprio(0);
        asm volatile("" ::: "memory");
        __builtin_amdgcn_s_barrier();            // all reads of tile t done
        asm volatile("" ::: "memory");

        slot = (slot == 2) ? 0 : slot + 1;
    }
#undef STAGE_A
#undef STAGE_B
#undef LDSA
#undef LDSB
    __syncthreads();                             // full drain before tileT reuse

    // ---- epilogue: two 128-row half-passes through unioned tileT (128 x 264) ----
    ushort* tileT = (ushort*)smem;
    const int prow = tid >> 2, pq = tid & 3;     // 4 threads per row, 64 cols each
#pragma unroll
    for (int h = 0; h < 2; ++h) {
        if (wrow == h) {                         // 4 waves own this half
#pragma unroll
            for (int n = 0; n < 4; ++n) {
                int col = wcol * 64 + n * 16 + lr;
                float bv = bias[bcol + col];
#pragma unroll
                for (int m = 0; m < 8; ++m) {
                    int row0 = m * 16 + kg * 4;
#pragma unroll
                    for (int r = 0; r < 4; ++r)
                        tileT[(row0 + r) * TSTR + col] = f2bf(acc[m][n][r] + bv);
                }
            }
        }
        __syncthreads();

        // coalesced bf16 store (512B runs per row)
#pragma unroll
        for (int it = 0; it < 8; ++it) {
            int idx = it * 512 + tid;
            int row = idx >> 5, ch = idx & 31;
            int grow = brow + h * 128 + row;
            if (grow < MROWS) {
                uint4 v = *(const uint4*)(&tileT[row * TSTR + ch * 8]);
                *(uint4*)(outu + (size_t)grow * 74000 + 42000 + bcol + ch * 8) = v;
            }
        }

        // per-row partial (max,sumexp) over 256 cols: 4 threads/row
        {
            int grow = brow + h * 128 + prow;
            const ushort* trow = &tileT[prow * TSTR + pq * 64];
            uint4 vv[8];
#pragma unroll
            for (int i = 0; i < 8; ++i) vv[i] = *(const uint4*)(trow + i * 8);
            float mx = -1e30f;
#pragma unroll
            for (int i = 0; i < 8; ++i) {
                mx = fmaxf(mx, fmaxf(fmaxf(bflo(vv[i].x), bfhi(vv[i].x)), fmaxf(bflo(vv[i].y), bfhi(vv[i].y))));
                mx = fmaxf(mx, fmaxf(fmaxf(bflo(vv[i].z), bfhi(vv[i].z)), fmaxf(bflo(vv[i].w), bfhi(vv[i].w))));
            }
            float sx = 0.f;
#pragma unroll
            for (int i = 0; i < 8; ++i) {
                sx += __expf(bflo(vv[i].x) - mx) + __expf(bfhi(vv[i].x) - mx)
                    + __expf(bflo(vv[i].y) - mx) + __expf(bfhi(vv[i].y) - mx)
                    + __expf(bflo(vv[i].z) - mx) + __expf(bfhi(vv[i].z) - mx)
                    + __expf(bflo(vv[i].w) - mx) + __expf(bfhi(vv[i].w) - mx);
            }
#pragma unroll
            for (int off = 1; off < 4; off <<= 1) {
                float om = __shfl_xor(mx, off), os = __shfl_xor(sx, off);
                float nm = fmaxf(mx, om);
                sx = sx * __expf(mx - nm) + os * __expf(om - nm);
                mx = nm;
            }
            if (pq == 0 && grow < MROWS) {
                pm[(size_t)ct * MROWS + grow] = mx;
                ps[(size_t)ct * MROWS + grow] = sx;
            }
        }
        __syncthreads();
    }
}

// ---------------- pass 2 (fused): lse reduce + gate + scatter + in-place normalize ----
__global__ __launch_bounds__(256) void norm_ext_kernel(float* __restrict__ out,
                                                       const float* __restrict__ pm,
                                                       const float* __restrict__ ps,
                                                       const float* __restrict__ dec,
                                                       const float* __restrict__ wc,
                                                       const float* __restrict__ bcp,
                                                       const float* __restrict__ attn,
                                                       const int* __restrict__ cte) {
    const int r = blockIdx.x;
    const int t = threadIdx.x;
    const int w = t >> 6, lane = t & 63;
    __shared__ float sm[4], ssv[4], red[4];
    __shared__ float lse_sh, csh;
    __shared__ float bins[VE];                   // 20000 B

    // lse partials (125 of them)
    float m = -1e30f, s = 0.f;
    if (t < NTILE) {
        m = pm[(size_t)t * MROWS + r];
        s = ps[(size_t)t * MROWS + r];
    }
    for (int off = 1; off < 64; off <<= 1) {
        float om = __shfl_xor(m, off), os = __shfl_xor(s, off);
        float nm = fmaxf(m, om);
        s = s * __expf(m - nm) + os * __expf(om - nm);
        m = nm;
    }
    if (lane == 0) { sm[w] = m; ssv[w] = s; }

    // gate partial: dot(dec[r], Wc), 2 elems/thread
    {
        float part = dec[(size_t)r * HH + t] * wc[t]
                   + dec[(size_t)r * HH + t + 256] * wc[t + 256];
        for (int off = 1; off < 64; off <<= 1) part += __shfl_xor(part, off);
        if (lane == 0) red[w] = part;
    }
    for (int v = t; v < VE; v += 256) bins[v] = 0.f;
    __syncthreads();

    if (t == 0) {
        float M = sm[0], S = ssv[0];
        for (int i = 1; i < 4; ++i) {
            float nm = fmaxf(M, sm[i]);
            S = S * __expf(M - nm) + ssv[i] * __expf(sm[i] - nm);
            M = nm;
        }
        lse_sh = M + __logf(S);
        float g = red[0] + red[1] + red[2] + red[3] + bcp[0];
        csh = 1.f / (1.f + __expf(-g));
    }
    __syncthreads();
    const float l = lse_sh;
    const float c = csh;

    // ext scatter into LDS bins
    if (t < SS) {
        float aw = attn[(size_t)r * SS + t] * (1.f - c);
        int idx = cte[t * BB + (r & 63)];
        if (idx != 0) atomicAdd(&bins[idx], aw);
    }

    // in-place normalize sweep: bf16 (row tail) -> fp32 log-softmax (row head).
    // Safe: fp32 write of uint4-index iw clobbers bf16 index ir only if ir < 2*iw - 5248;
    // barriers every 2 iterations bound skew to 512 indices (needs 256n > 4226, max n=15).
    const uint4* gsrc = (const uint4*)((const ushort*)out + (size_t)r * 74000 + 42000);
    float4* orow = (float4*)(out + (size_t)r * LDC);
    for (int n = 0; n < 16; ++n) {
        int i = t + 256 * n;
        if (i < VT / 8) {
            uint4 v = gsrc[i];
            float4 a, b;
            a.x = bflo(v.x) - l; a.y = bfhi(v.x) - l;
            a.z = bflo(v.y) - l; a.w = bfhi(v.y) - l;
            b.x = bflo(v.z) - l; b.y = bfhi(v.z) - l;
            b.z = bflo(v.w) - l; b.w = bfhi(v.w) - l;
            orow[2 * i]     = a;
            orow[2 * i + 1] = b;
        }
        if ((n & 1) == 1) __syncthreads();
    }
    __syncthreads();

    float4* eo = (float4*)(out + (size_t)r * LDC + VT);
    for (int v = t; v < VE / 4; v += 256) {
        float4 x;
        x.x = __logf(fminf(fmaxf(bins[4 * v + 0], 0.001f), 0.999f));
        x.y = __logf(fminf(fmaxf(bins[4 * v + 1], 0.001f), 0.999f));
        x.z = __logf(fminf(fmaxf(bins[4 * v + 2], 0.001f), 0.999f));
        x.w = __logf(fminf(fmaxf(bins[4 * v + 3], 0.001f), 0.999f));
        eo[v] = x;
    }
}

extern "C" void kernel_launch(void* const* d_in, const int* in_sizes, int n_in,
                              void* d_out, int out_size, void* d_ws, size_t ws_size,
                              hipStream_t stream) {
    const float* hidden = (const float*)d_in[0];
    const float* dec    = (const float*)d_in[1];
    // d_in[2] = concat_c, unused by the reference
    const float* attn   = (const float*)d_in[3];
    const int*   cte    = (const int*)d_in[4];
    const float* W      = (const float*)d_in[5];
    const float* bias   = (const float*)d_in[6];
    const float* Wc     = (const float*)d_in[7];
    const float* bc     = (const float*)d_in[8];
    float* out = (float*)d_out;

    ushort* wsB = (ushort*)d_ws;                       // W bf16  [32000][512]  32.77 MB
    ushort* wsA = wsB + (size_t)VT * HH;               // hidden bf16 [3328][512] (padded)
    float*  pm  = (float*)(wsA + (size_t)MPAD * HH);   // partial max [125][3200]
    float*  ps  = pm + (size_t)NTILE * MROWS;          // partial sum [125][3200]

    convert_kernel<<<17664, 256, 0, stream>>>(W, hidden, wsB, wsA);
    gemm_kernel<<<NWG, 512, 0, stream>>>(wsA, wsB, bias, (ushort*)out, pm, ps);
    norm_ext_kernel<<<MROWS, 256, 0, stream>>>(out, pm, ps, dec, Wc, bc, attn, cte);
}